// Round 2
// baseline (244.129 us; speedup 1.0000x reference)
//
#include <hip/hip_runtime.h>
#include <hip/hip_cooperative_groups.h>

namespace cg = cooperative_groups;

typedef unsigned short u16;
typedef unsigned int u32;
typedef __bf16 bf16x8 __attribute__((ext_vector_type(8)));
typedef float f32x4 __attribute__((ext_vector_type(4)));

__device__ __forceinline__ float bf2f(u16 v) {
    union { u32 u; float f; } c; c.u = ((u32)v) << 16; return c.f;
}
__device__ __forceinline__ u16 f2bf(float f) {
    union { float f; u32 u; } c; c.f = f;
    u32 u = c.u + 0x7fffu + ((c.u >> 16) & 1u);   // RNE
    return (u16)(u >> 16);
}

// ===================== FUSED single cooperative kernel =====================
// 256 blocks x 512 threads (1 block/CU, co-resident). Phases separated by grid.sync():
// P0: cond matvec (waves 0-3) || w_qkv/w_out -> bf16 (waves 4-7)
// P1: rmsnorm (1 wave per token row)
// P2: qkv GEMM, 3x 64x64 tiles/block, 8-wave (wm=w>>1 16-row, wn=w&1 32-col), RoPE+headnorm epilogue
// P3: neighborhood attention (1 tile/block)
// P4: out GEMM + skip, 1x 64x64 tile/block
__global__ __launch_bounds__(512) void fused_all(
    const float* __restrict__ cond, const float* __restrict__ w_cond,
    const float* __restrict__ w_qkv, const float* __restrict__ w_out,
    const float* __restrict__ x, const float* __restrict__ pos,
    const float* __restrict__ scale,
    float* __restrict__ ns, u16* __restrict__ wqkvb, u16* __restrict__ woutb,
    u16* __restrict__ xn, u16* __restrict__ qp, u16* __restrict__ kp,
    u16* __restrict__ vp, u16* __restrict__ ob, float* __restrict__ out)
{
    __shared__ __align__(16) u16 SM[29824];   // 59648 B: max(gemm 40960, attn 59648)
    cg::grid_group gg = cg::this_grid();

    int tid = threadIdx.x, lane = tid & 63, w = tid >> 6;   // w 0..7
    int bid = blockIdx.x;                                    // 0..255
    int m = lane & 15, quad = lane >> 4, kq = quad * 8;

    // ---------------- P0: cond matvec || weight convert
    if (w < 4) {
        int wid = bid * 4 + w;             // 0..1023
        int n = wid >> 9, c = wid & 511;
        const float* cp = cond + n * 768;
        const float* wp = w_cond + (size_t)c * 768;
        float s = 0.f;
        #pragma unroll
        for (int j = 0; j < 12; j++)
            s += cp[lane + j * 64] * wp[lane + j * 64];
        #pragma unroll
        for (int d = 1; d < 64; d <<= 1) s += __shfl_xor(s, d);
        if (lane == 0) ns[wid] = s + 1.f;
    } else {
        int gt = (bid * 4 + (w - 4)) * 64 + lane;   // 0..65535
        #pragma unroll
        for (int i = 0; i < 4; i++) {
            int task = gt + i * 65536;              // 0..262143 float4-tasks
            const float* src; u16* dst; int idx;
            if (task < 196608) { src = w_qkv; dst = wqkvb; idx = task; }
            else               { src = w_out; dst = woutb; idx = task - 196608; }
            float4 v = *(const float4*)(src + (size_t)idx * 4);
            ushort4 o; o.x = f2bf(v.x); o.y = f2bf(v.y); o.z = f2bf(v.z); o.w = f2bf(v.w);
            *(ushort4*)(dst + (size_t)idx * 4) = o;
        }
    }
    gg.sync();

    // ---------------- P1: rmsnorm, one wave per token row
    {
        int p = bid * 8 + w;               // 0..2047
        int n = p >> 10;
        const float* xp = x + (size_t)p * 512;
        const float* nsp = ns + n * 512;
        float4 v0 = *(const float4*)(xp + lane * 4);
        float4 v1 = *(const float4*)(xp + 256 + lane * 4);
        float ss = v0.x * v0.x + v0.y * v0.y + v0.z * v0.z + v0.w * v0.w
                 + v1.x * v1.x + v1.y * v1.y + v1.z * v1.z + v1.w * v1.w;
        #pragma unroll
        for (int d = 1; d < 64; d <<= 1) ss += __shfl_xor(ss, d);
        float inv = rsqrtf(ss * (1.f / 512.f) + 1e-6f);
        float4 n0 = *(const float4*)(nsp + lane * 4);
        float4 n1 = *(const float4*)(nsp + 256 + lane * 4);
        ushort4 o0, o1;
        o0.x = f2bf(v0.x * n0.x * inv); o0.y = f2bf(v0.y * n0.y * inv);
        o0.z = f2bf(v0.z * n0.z * inv); o0.w = f2bf(v0.w * n0.w * inv);
        o1.x = f2bf(v1.x * n1.x * inv); o1.y = f2bf(v1.y * n1.y * inv);
        o1.z = f2bf(v1.z * n1.z * inv); o1.w = f2bf(v1.w * n1.w * inv);
        *(ushort4*)(xn + (size_t)p * 512 + lane * 4) = o0;
        *(ushort4*)(xn + (size_t)p * 512 + 256 + lane * 4) = o1;
    }
    gg.sync();

    // ---------------- P2: qkv GEMM, 3 tiles per block
    {
        u16 (*As)[64][40] = (u16 (*)[64][40])SM;
        u16 (*Bs)[64][40] = (u16 (*)[64][40])(SM + 10240);
        int wm = w >> 1, wn = w & 1;       // 4 x 16-row groups, 2 x 32-col halves
        int lrow = tid >> 3, lc16 = (tid & 7) * 16;
        int sA = lc16 >> 5, off = lc16 & 31;
        int rlbase = wm * 16 + quad * 4;

        for (int it = 0; it < 3; it++) {
            int t = bid + it * 256;        // 0..767
            int bm = (t & 31) * 64;
            int by = t >> 5;               // 0..23
            int bn = by * 64;
            int qk = by >> 3, h = by & 7;
            const u16* Ap = xn + (size_t)(bm + lrow) * 512 + lc16;
            const u16* Bp = wqkvb + (size_t)(bn + lrow) * 512 + lc16;
            f32x4 acc0 = {0.f, 0.f, 0.f, 0.f};
            f32x4 acc1 = {0.f, 0.f, 0.f, 0.f};
            __syncthreads();               // SM reuse guard (red/As across tiles/phases)
            for (int k0 = 0; k0 < 512; k0 += 128) {
                *(uint4*)&As[sA][lrow][off]     = *(const uint4*)(Ap + k0);
                *(uint4*)&As[sA][lrow][off + 8] = *(const uint4*)(Ap + k0 + 8);
                *(uint4*)&Bs[sA][lrow][off]     = *(const uint4*)(Bp + k0);
                *(uint4*)&Bs[sA][lrow][off + 8] = *(const uint4*)(Bp + k0 + 8);
                __syncthreads();
                #pragma unroll
                for (int kk = 0; kk < 4; kk++) {
                    bf16x8 a  = *(const bf16x8*)&As[kk][wm * 16 + m][kq];
                    bf16x8 b0 = *(const bf16x8*)&Bs[kk][wn * 32 + m][kq];
                    bf16x8 b1 = *(const bf16x8*)&Bs[kk][wn * 32 + 16 + m][kq];
                    acc0 = __builtin_amdgcn_mfma_f32_16x16x32_bf16(a, b0, acc0, 0, 0, 0);
                    acc1 = __builtin_amdgcn_mfma_f32_16x16x32_bf16(a, b1, acc1, 0, 0, 0);
                }
                __syncthreads();
            }
            // epilogue: head-norm (cross-wave over wn) + RoPE for q/k
            float invn[4];
            if (qk < 2) {
                float* red = (float*)SM;   // [64][2]
                #pragma unroll
                for (int reg = 0; reg < 4; reg++) {
                    float pa = acc0[reg] * acc0[reg] + acc1[reg] * acc1[reg];
                    #pragma unroll
                    for (int d = 1; d < 16; d <<= 1) pa += __shfl_xor(pa, d);
                    if (m == 0) red[(rlbase + reg) * 2 + wn] = pa;
                }
                __syncthreads();
                float sq = sqrtf(scale[h]);
                #pragma unroll
                for (int reg = 0; reg < 4; reg++) {
                    int rl = rlbase + reg;
                    invn[reg] = sq * rsqrtf(red[rl * 2] + red[rl * 2 + 1] + 1e-6f);
                }
            }
            u16* plane = (qk == 0) ? qp : (qk == 1) ? kp : vp;
            float fr = 3.14159265358979323846f * expf((float)(m * 8 + h) * (2.302585092994046f / 128.f));
            #pragma unroll
            for (int reg = 0; reg < 4; reg++) {
                int rl = rlbase + reg;
                int p = bm + rl;
                size_t basep = ((size_t)((p >> 10) * 8 + h) * 1024 + (p & 1023)) * 64;
                float v0 = acc0[reg], v1 = acc1[reg];
                if (qk < 2) {
                    float ivn = invn[reg];
                    v0 *= ivn; v1 *= ivn;
                    if (wn == 0) {   // dims 0..15 pair with 16..31: register-local rotation
                        float th = pos[p] * fr;
                        float cs = cosf(th), sn = sinf(th);
                        float o0 = v0 * cs - v1 * sn;
                        float o1 = v1 * cs + v0 * sn;
                        v0 = o0; v1 = o1;
                    }
                }
                plane[basep + wn * 32 + m]      = f2bf(v0);
                plane[basep + wn * 32 + 16 + m] = f2bf(v1);
            }
        }
    }
    gg.sync();

    // ---------------- P3: neighborhood attention, one (n,h,8x8) tile per block
    {
        u16* Kb = SM;            // [nb][64] stride 72; reused as Vt [64][224] stride 234
        u16* Sb = SM + 14976;    // S fp16 then P bf16, row stride 232
        int n = bid >> 7, h = (bid >> 4) & 7, t = bid & 15;
        int ti = (t >> 2) * 8, tj = (t & 3) * 8;
        int r0 = min(max(ti - 3, 0), 18), c0 = min(max(tj - 3, 0), 18);
        const u16* qpl = qp + ((size_t)(n * 8 + h) << 16);
        const u16* kpl = kp + ((size_t)(n * 8 + h) << 16);
        const u16* vpl = vp + ((size_t)(n * 8 + h) << 16);

        __syncthreads();   // SM reuse guard after P2 epilogue reads
        for (int g = tid; g < 1568; g += 512) {
            int nb = g >> 3, k8 = (g & 7) << 3;
            int ar = nb / 14, ac = nb - ar * 14;
            *(uint4*)&Kb[nb * 72 + k8] =
                *(const uint4*)&kpl[(size_t)((r0 + ar) * 32 + c0 + ac) * 64 + k8];
        }
        __syncthreads();

        int rg = w & 3, half = w >> 2;
        {
            int r = rg * 16 + m;
            int tok = (ti + (r >> 3)) * 32 + (tj + (r & 7));
            bf16x8 qf0 = *(const bf16x8*)&qpl[(size_t)tok * 64 + quad * 8];
            bf16x8 qf1 = *(const bf16x8*)&qpl[(size_t)tok * 64 + 32 + quad * 8];
            _Float16* sp = (_Float16*)Sb;
            int ntb = half * 7;
            int ntn = 7 - half;
            for (int i = 0; i < ntn; i++) {
                int nt = ntb + i;
                f32x4 acc = {0.f, 0.f, 0.f, 0.f};
                bf16x8 b0 = *(const bf16x8*)&Kb[(nt * 16 + m) * 72 + quad * 8];
                bf16x8 b1 = *(const bf16x8*)&Kb[(nt * 16 + m) * 72 + 32 + quad * 8];
                __builtin_amdgcn_s_setprio(1);
                acc = __builtin_amdgcn_mfma_f32_16x16x32_bf16(qf0, b0, acc, 0, 0, 0);
                acc = __builtin_amdgcn_mfma_f32_16x16x32_bf16(qf1, b1, acc, 0, 0, 0);
                __builtin_amdgcn_s_setprio(0);
                #pragma unroll
                for (int reg = 0; reg < 4; reg++)
                    sp[(rg * 16 + quad * 4 + reg) * 232 + nt * 16 + m] = (_Float16)acc[reg];
            }
        }
        __syncthreads();

        for (int g = tid; g < 1568; g += 512) {
            int nb = g >> 3, k8 = (g & 7) << 3;
            int ar = nb / 14, ac = nb - ar * 14;
            uint4 v4 = *(const uint4*)&vpl[(size_t)((r0 + ar) * 32 + c0 + ac) * 64 + k8];
            u32 uu[4] = {v4.x, v4.y, v4.z, v4.w};
            #pragma unroll
            for (int e = 0; e < 4; e++) {
                Kb[(k8 + 2 * e) * 234 + nb]     = (u16)(uu[e] & 0xffff);
                Kb[(k8 + 2 * e + 1) * 234 + nb] = (u16)(uu[e] >> 16);
            }
        }
        for (int g = tid; g < 1792; g += 512) {
            int d = g / 28, nb = 196 + (g - d * 28);
            Kb[d * 234 + nb] = 0;
        }

        {
            int l16 = lane & 15, g4 = lane >> 4;
            #pragma unroll
            for (int it = 0; it < 2; it++) {
                int rr = w * 8 + it * 4 + g4;
                int i2 = ti + (rr >> 3), j2 = tj + (rr & 7);
                int alo = min(max(i2 - 3, 0), 25) - r0;
                int blo = min(max(j2 - 3, 0), 25) - c0;
                const _Float16* sp = (const _Float16*)&Sb[rr * 232];
                float vals[14];
                float mx = -1e30f;
                #pragma unroll
                for (int c = 0; c < 14; c++) {
                    int col = l16 + c * 16;
                    float v = -1e30f;
                    if (col < 196) {
                        int ar = col / 14, ac = col - ar * 14;
                        if (ar >= alo && ar < alo + 7 && ac >= blo && ac < blo + 7)
                            v = (float)sp[col];
                    }
                    vals[c] = v; mx = fmaxf(mx, v);
                }
                #pragma unroll
                for (int d = 1; d < 16; d <<= 1) mx = fmaxf(mx, __shfl_xor(mx, d));
                float s = 0.f;
                #pragma unroll
                for (int c = 0; c < 14; c++) {
                    float e = exp2f((vals[c] - mx) * 1.44269504f);
                    vals[c] = e; s += e;
                }
                #pragma unroll
                for (int d = 1; d < 16; d <<= 1) s += __shfl_xor(s, d);
                float rs = __frcp_rn(s);
                u16* pp = &Sb[rr * 232];
                #pragma unroll
                for (int c = 0; c < 14; c++)
                    pp[l16 + c * 16] = f2bf(vals[c] * rs);
            }
        }
        __syncthreads();

        f32x4 oacc[2];
        {
            f32x4 z = {0.f, 0.f, 0.f, 0.f};
            oacc[0] = z; oacc[1] = z;
        }
        #pragma unroll
        for (int ks = 0; ks < 7; ks++) {
            bf16x8 pa = *(const bf16x8*)&Sb[(rg * 16 + m) * 232 + ks * 32 + quad * 8];
            __builtin_amdgcn_s_setprio(1);
            #pragma unroll
            for (int j = 0; j < 2; j++) {
                int nt = half * 2 + j;
                int ad = (nt * 16 + m) * 234 + ks * 32 + quad * 8;
                union { u32 u[4]; bf16x8 v; } vb;
                vb.u[0] = *(const u32*)&Kb[ad];
                vb.u[1] = *(const u32*)&Kb[ad + 2];
                vb.u[2] = *(const u32*)&Kb[ad + 4];
                vb.u[3] = *(const u32*)&Kb[ad + 6];
                oacc[j] = __builtin_amdgcn_mfma_f32_16x16x32_bf16(pa, vb.v, oacc[j], 0, 0, 0);
            }
            __builtin_amdgcn_s_setprio(0);
        }
        #pragma unroll
        for (int j = 0; j < 2; j++) {
            int nt = half * 2 + j;
            #pragma unroll
            for (int reg = 0; reg < 4; reg++) {
                int rr = rg * 16 + quad * 4 + reg;
                int tok = (ti + (rr >> 3)) * 32 + (tj + (rr & 7));
                ob[(size_t)(n * 1024 + tok) * 512 + h * 64 + nt * 16 + m] = f2bf(oacc[j][reg]);
            }
        }
    }
    gg.sync();

    // ---------------- P4: out GEMM + skip, one 64x64 tile per block
    {
        u16 (*As)[64][40] = (u16 (*)[64][40])SM;
        u16 (*Bs)[64][40] = (u16 (*)[64][40])(SM + 10240);
        int wm = w >> 1, wn = w & 1;
        int lrow = tid >> 3, lc16 = (tid & 7) * 16;
        int sA = lc16 >> 5, off = lc16 & 31;
        int bm = (bid & 31) * 64, bn = (bid >> 5) * 64;
        const u16* Ap = ob + (size_t)(bm + lrow) * 512 + lc16;
        const u16* Bp = woutb + (size_t)(bn + lrow) * 512 + lc16;
        f32x4 acc0 = {0.f, 0.f, 0.f, 0.f};
        f32x4 acc1 = {0.f, 0.f, 0.f, 0.f};
        __syncthreads();   // SM reuse guard after P3
        for (int k0 = 0; k0 < 512; k0 += 128) {
            *(uint4*)&As[sA][lrow][off]     = *(const uint4*)(Ap + k0);
            *(uint4*)&As[sA][lrow][off + 8] = *(const uint4*)(Ap + k0 + 8);
            *(uint4*)&Bs[sA][lrow][off]     = *(const uint4*)(Bp + k0);
            *(uint4*)&Bs[sA][lrow][off + 8] = *(const uint4*)(Bp + k0 + 8);
            __syncthreads();
            #pragma unroll
            for (int kk = 0; kk < 4; kk++) {
                bf16x8 a  = *(const bf16x8*)&As[kk][wm * 16 + m][kq];
                bf16x8 b0 = *(const bf16x8*)&Bs[kk][wn * 32 + m][kq];
                bf16x8 b1 = *(const bf16x8*)&Bs[kk][wn * 32 + 16 + m][kq];
                acc0 = __builtin_amdgcn_mfma_f32_16x16x32_bf16(a, b0, acc0, 0, 0, 0);
                acc1 = __builtin_amdgcn_mfma_f32_16x16x32_bf16(a, b1, acc1, 0, 0, 0);
            }
            __syncthreads();
        }
        #pragma unroll
        for (int reg = 0; reg < 4; reg++) {
            int row = bm + wm * 16 + quad * 4 + reg;
            int col = bn + wn * 32 + m;
            size_t i0 = (size_t)row * 512 + col;
            out[i0]      = acc0[reg] + x[i0];
            out[i0 + 16] = acc1[reg] + x[i0 + 16];
        }
    }
}

// ===================== Fallback path (previous 5-kernel pipeline) =====================

__global__ __launch_bounds__(256) void cond_prepw_kernel(
    const float* __restrict__ cond, const float* __restrict__ w_cond, float* __restrict__ ns,
    const float* __restrict__ w_qkv, const float* __restrict__ w_out,
    u16* __restrict__ wqkvb, u16* __restrict__ woutb)
{
    int b = blockIdx.x;
    if (b < 256) {
        int lane = threadIdx.x & 63;
        int wid = b * 4 + (threadIdx.x >> 6);
        int n = wid >> 9, c = wid & 511;
        const float* cp = cond + n * 768;
        const float* wp = w_cond + (size_t)c * 768;
        float s = 0.f;
        #pragma unroll
        for (int j = 0; j < 12; j++)
            s += cp[lane + j * 64] * wp[lane + j * 64];
        #pragma unroll
        for (int d = 1; d < 64; d <<= 1) s += __shfl_xor(s, d);
        if (lane == 0) ns[wid] = s + 1.f;
    } else {
        const float* src; u16* dst; size_t i4;
        if (b < 1024) { src = w_qkv; dst = wqkvb; i4 = (size_t)(b - 256)  * 1024 + threadIdx.x * 4; }
        else          { src = w_out; dst = woutb; i4 = (size_t)(b - 1024) * 1024 + threadIdx.x * 4; }
        float4 v = *(const float4*)(src + i4);
        ushort4 o; o.x = f2bf(v.x); o.y = f2bf(v.y); o.z = f2bf(v.z); o.w = f2bf(v.w);
        *(ushort4*)(dst + i4) = o;
    }
}

__global__ __launch_bounds__(256) void rms_kernel(
    const float* __restrict__ x, const float* __restrict__ ns, u16* __restrict__ xn)
{
    int b = blockIdx.x;
    int w = threadIdx.x >> 6, lane = threadIdx.x & 63;
    int p = b * 4 + w;
    int n = p >> 10;
    const float* xp = x + (size_t)p * 512;
    const float* nsp = ns + n * 512;
    float4 v0 = *(const float4*)(xp + lane * 4);
    float4 v1 = *(const float4*)(xp + 256 + lane * 4);
    float ss = v0.x * v0.x + v0.y * v0.y + v0.z * v0.z + v0.w * v0.w
             + v1.x * v1.x + v1.y * v1.y + v1.z * v1.z + v1.w * v1.w;
    #pragma unroll
    for (int d = 1; d < 64; d <<= 1) ss += __shfl_xor(ss, d);
    float inv = rsqrtf(ss * (1.f / 512.f) + 1e-6f);
    float4 n0 = *(const float4*)(nsp + lane * 4);
    float4 n1 = *(const float4*)(nsp + 256 + lane * 4);
    ushort4 o0, o1;
    o0.x = f2bf(v0.x * n0.x * inv); o0.y = f2bf(v0.y * n0.y * inv);
    o0.z = f2bf(v0.z * n0.z * inv); o0.w = f2bf(v0.w * n0.w * inv);
    o1.x = f2bf(v1.x * n1.x * inv); o1.y = f2bf(v1.y * n1.y * inv);
    o1.z = f2bf(v1.z * n1.z * inv); o1.w = f2bf(v1.w * n1.w * inv);
    *(ushort4*)(xn + (size_t)p * 512 + lane * 4) = o0;
    *(ushort4*)(xn + (size_t)p * 512 + 256 + lane * 4) = o1;
}

__global__ __launch_bounds__(256) void gemm_qkv(
    const u16* __restrict__ A, const u16* __restrict__ B,
    const float* __restrict__ pos, const float* __restrict__ scale,
    u16* __restrict__ qp, u16* __restrict__ kp, u16* __restrict__ vp)
{
    __shared__ __align__(16) u16 As[4][64][40];
    __shared__ __align__(16) u16 Bs[4][64][40];
    int tid = threadIdx.x;
    int lane = tid & 63;
    int w = tid >> 6;
    int wm = w >> 1, wn = w & 1;
    int bm = blockIdx.x * 64, bn = blockIdx.y * 64;
    int qk = blockIdx.y >> 3, h = blockIdx.y & 7;
    int lrow = tid >> 2, lc8 = (tid & 3) * 8;

    f32x4 zero = {0.f, 0.f, 0.f, 0.f};
    f32x4 acc[2][2];
    acc[0][0] = zero; acc[0][1] = zero; acc[1][0] = zero; acc[1][1] = zero;

    const u16* Ap = A + (size_t)(bm + lrow) * 512 + lc8;
    const u16* Bp = B + (size_t)(bn + lrow) * 512 + lc8;
    int m = lane & 15, quad = lane >> 4, kq = quad * 8;

    for (int k0 = 0; k0 < 512; k0 += 128) {
        #pragma unroll
        for (int s = 0; s < 4; s++) {
            *(uint4*)&As[s][lrow][lc8] = *(const uint4*)(Ap + k0 + s * 32);
            *(uint4*)&Bs[s][lrow][lc8] = *(const uint4*)(Bp + k0 + s * 32);
        }
        __syncthreads();
        #pragma unroll
        for (int kk = 0; kk < 4; kk++) {
            bf16x8 a0 = *(const bf16x8*)&As[kk][wm * 32 + m][kq];
            bf16x8 a1 = *(const bf16x8*)&As[kk][wm * 32 + 16 + m][kq];
            bf16x8 b0 = *(const bf16x8*)&Bs[kk][wn * 32 + m][kq];
            bf16x8 b1 = *(const bf16x8*)&Bs[kk][wn * 32 + 16 + m][kq];
            acc[0][0] = __builtin_amdgcn_mfma_f32_16x16x32_bf16(a0, b0, acc[0][0], 0, 0, 0);
            acc[0][1] = __builtin_amdgcn_mfma_f32_16x16x32_bf16(a0, b1, acc[0][1], 0, 0, 0);
            acc[1][0] = __builtin_amdgcn_mfma_f32_16x16x32_bf16(a1, b0, acc[1][0], 0, 0, 0);
            acc[1][1] = __builtin_amdgcn_mfma_f32_16x16x32_bf16(a1, b1, acc[1][1], 0, 0, 0);
        }
        __syncthreads();
    }

    float invn[2][4];
    if (qk < 2) {
        float* red = (float*)As;
        #pragma unroll
        for (int ri = 0; ri < 2; ri++)
        #pragma unroll
        for (int reg = 0; reg < 4; reg++) {
            float pa = acc[ri][0][reg] * acc[ri][0][reg]
                     + acc[ri][1][reg] * acc[ri][1][reg];
            #pragma unroll
            for (int d = 1; d < 16; d <<= 1) pa += __shfl_xor(pa, d);
            if (m == 0) red[(wm * 32 + ri * 16 + quad * 4 + reg) * 2 + wn] = pa;
        }
        __syncthreads();
        float sq = sqrtf(scale[h]);
        #pragma unroll
        for (int ri = 0; ri < 2; ri++)
        #pragma unroll
        for (int reg = 0; reg < 4; reg++) {
            int rl = wm * 32 + ri * 16 + quad * 4 + reg;
            invn[ri][reg] = sq * rsqrtf(red[rl * 2] + red[rl * 2 + 1] + 1e-6f);
        }
    }
    u16* plane = (qk == 0) ? qp : (qk == 1) ? kp : vp;
    float fr = 3.14159265358979323846f * expf((float)(m * 8 + h) * (2.302585092994046f / 128.f));
    #pragma unroll
    for (int ri = 0; ri < 2; ri++)
    #pragma unroll
    for (int reg = 0; reg < 4; reg++) {
        int rl = wm * 32 + ri * 16 + quad * 4 + reg;
        int p = bm + rl;
        size_t basep = ((size_t)((p >> 10) * 8 + h) * 1024 + (p & 1023)) * 64;
        float v0 = acc[ri][0][reg], v1 = acc[ri][1][reg];
        if (qk < 2) {
            float ivn = invn[ri][reg];
            v0 *= ivn; v1 *= ivn;
            if (wn == 0) {
                float th = pos[p] * fr;
                float cs = cosf(th), sn = sinf(th);
                float o0 = v0 * cs - v1 * sn;
                float o1 = v1 * cs + v0 * sn;
                v0 = o0; v1 = o1;
            }
        }
        plane[basep + wn * 32 + m]      = f2bf(v0);
        plane[basep + wn * 32 + 16 + m] = f2bf(v1);
    }
}

__global__ __launch_bounds__(256) void gemm_out(
    const u16* __restrict__ A, const u16* __restrict__ B,
    float* __restrict__ C, const float* __restrict__ skip, int N, int K)
{
    __shared__ __align__(16) u16 As[4][64][40];
    __shared__ __align__(16) u16 Bs[4][64][40];
    int tid = threadIdx.x;
    int lane = tid & 63;
    int w = tid >> 6;
    int wm = w >> 1, wn = w & 1;
    int bm = blockIdx.x * 64, bn = blockIdx.y * 64;
    int lrow = tid >> 2, lc8 = (tid & 3) * 8;

    f32x4 zero = {0.f, 0.f, 0.f, 0.f};
    f32x4 acc[2][2];
    acc[0][0] = zero; acc[0][1] = zero; acc[1][0] = zero; acc[1][1] = zero;

    const u16* Ap = A + (size_t)(bm + lrow) * K + lc8;
    const u16* Bp = B + (size_t)(bn + lrow) * K + lc8;
    int r = lane & 15, kq = (lane >> 4) * 8;

    for (int k0 = 0; k0 < K; k0 += 128) {
        #pragma unroll
        for (int s = 0; s < 4; s++) {
            *(uint4*)&As[s][lrow][lc8] = *(const uint4*)(Ap + k0 + s * 32);
            *(uint4*)&Bs[s][lrow][lc8] = *(const uint4*)(Bp + k0 + s * 32);
        }
        __syncthreads();
        #pragma unroll
        for (int kk = 0; kk < 4; kk++) {
            bf16x8 a0 = *(const bf16x8*)&As[kk][wm * 32 + r][kq];
            bf16x8 a1 = *(const bf16x8*)&As[kk][wm * 32 + 16 + r][kq];
            bf16x8 b0 = *(const bf16x8*)&Bs[kk][wn * 32 + r][kq];
            bf16x8 b1 = *(const bf16x8*)&Bs[kk][wn * 32 + 16 + r][kq];
            acc[0][0] = __builtin_amdgcn_mfma_f32_16x16x32_bf16(a0, b0, acc[0][0], 0, 0, 0);
            acc[0][1] = __builtin_amdgcn_mfma_f32_16x16x32_bf16(a0, b1, acc[0][1], 0, 0, 0);
            acc[1][0] = __builtin_amdgcn_mfma_f32_16x16x32_bf16(a1, b0, acc[1][0], 0, 0, 0);
            acc[1][1] = __builtin_amdgcn_mfma_f32_16x16x32_bf16(a1, b1, acc[1][1], 0, 0, 0);
        }
        __syncthreads();
    }

    #pragma unroll
    for (int ri = 0; ri < 2; ri++)
    #pragma unroll
    for (int ci = 0; ci < 2; ci++) {
        int col = bn + wn * 32 + ci * 16 + (lane & 15);
        int row0 = bm + wm * 32 + ri * 16 + (lane >> 4) * 4;
        #pragma unroll
        for (int reg = 0; reg < 4; reg++) {
            size_t idx = (size_t)(row0 + reg) * N + col;
            C[idx] = acc[ri][ci][reg] + skip[idx];
        }
    }
}

__global__ __launch_bounds__(512) void attn_mfma(
    const u16* __restrict__ qp, const u16* __restrict__ kp, const u16* __restrict__ vp,
    u16* __restrict__ ob)
{
    __shared__ __align__(16) u16 Kb[208 * 72];
    __shared__ __align__(16) u16 Sb[64 * 232];

    int tid = threadIdx.x, lane = tid & 63, w = tid >> 6;
    int bx = blockIdx.x;
    int n = bx >> 7, h = (bx >> 4) & 7, t = bx & 15;
    int ti = (t >> 2) * 8, tj = (t & 3) * 8;
    int r0 = min(max(ti - 3, 0), 18), c0 = min(max(tj - 3, 0), 18);
    const u16* qpl = qp + ((size_t)(n * 8 + h) << 16);
    const u16* kpl = kp + ((size_t)(n * 8 + h) << 16);
    const u16* vpl = vp + ((size_t)(n * 8 + h) << 16);

    for (int g = tid; g < 1568; g += 512) {
        int nb = g >> 3, k8 = (g & 7) << 3;
        int ar = nb / 14, ac = nb - ar * 14;
        *(uint4*)&Kb[nb * 72 + k8] =
            *(const uint4*)&kpl[(size_t)((r0 + ar) * 32 + c0 + ac) * 64 + k8];
    }
    __syncthreads();

    int m = lane & 15, quad = lane >> 4;
    int rg = w & 3, half = w >> 2;
    {
        int r = rg * 16 + m;
        int tok = (ti + (r >> 3)) * 32 + (tj + (r & 7));
        bf16x8 qf0 = *(const bf16x8*)&qpl[(size_t)tok * 64 + quad * 8];
        bf16x8 qf1 = *(const bf16x8*)&qpl[(size_t)tok * 64 + 32 + quad * 8];
        _Float16* sp = (_Float16*)Sb;
        int ntb = half * 7;
        int ntn = 7 - half;
        for (int i = 0; i < ntn; i++) {
            int nt = ntb + i;
            f32x4 acc = {0.f, 0.f, 0.f, 0.f};
            bf16x8 b0 = *(const bf16x8*)&Kb[(nt * 16 + m) * 72 + quad * 8];
            bf16x8 b1 = *(const bf16x8*)&Kb[(nt * 16 + m) * 72 + 32 + quad * 8];
            __builtin_amdgcn_s_setprio(1);
            acc = __builtin_amdgcn_mfma_f32_16x16x32_bf16(qf0, b0, acc, 0, 0, 0);
            acc = __builtin_amdgcn_mfma_f32_16x16x32_bf16(qf1, b1, acc, 0, 0, 0);
            __builtin_amdgcn_s_setprio(0);
            #pragma unroll
            for (int reg = 0; reg < 4; reg++)
                sp[(rg * 16 + quad * 4 + reg) * 232 + nt * 16 + m] = (_Float16)acc[reg];
        }
    }
    __syncthreads();

    for (int g = tid; g < 1568; g += 512) {
        int nb = g >> 3, k8 = (g & 7) << 3;
        int ar = nb / 14, ac = nb - ar * 14;
        uint4 v4 = *(const uint4*)&vpl[(size_t)((r0 + ar) * 32 + c0 + ac) * 64 + k8];
        u32 uu[4] = {v4.x, v4.y, v4.z, v4.w};
        #pragma unroll
        for (int e = 0; e < 4; e++) {
            Kb[(k8 + 2 * e) * 234 + nb]     = (u16)(uu[e] & 0xffff);
            Kb[(k8 + 2 * e + 1) * 234 + nb] = (u16)(uu[e] >> 16);
        }
    }
    for (int g = tid; g < 1792; g += 512) {
        int d = g / 28, nb = 196 + (g - d * 28);
        Kb[d * 234 + nb] = 0;
    }

    {
        int l16 = lane & 15, g4 = lane >> 4;
        #pragma unroll
        for (int it = 0; it < 2; it++) {
            int rr = w * 8 + it * 4 + g4;
            int i2 = ti + (rr >> 3), j2 = tj + (rr & 7);
            int alo = min(max(i2 - 3, 0), 25) - r0;
            int blo = min(max(j2 - 3, 0), 25) - c0;
            const _Float16* sp = (const _Float16*)&Sb[rr * 232];
            float vals[14];
            float mx = -1e30f;
            #pragma unroll
            for (int c = 0; c < 14; c++) {
                int col = l16 + c * 16;
                float v = -1e30f;
                if (col < 196) {
                    int ar = col / 14, ac = col - ar * 14;
                    if (ar >= alo && ar < alo + 7 && ac >= blo && ac < blo + 7)
                        v = (float)sp[col];
                }
                vals[c] = v; mx = fmaxf(mx, v);
            }
            #pragma unroll
            for (int d = 1; d < 16; d <<= 1) mx = fmaxf(mx, __shfl_xor(mx, d));
            float s = 0.f;
            #pragma unroll
            for (int c = 0; c < 14; c++) {
                float e = exp2f((vals[c] - mx) * 1.44269504f);
                vals[c] = e; s += e;
            }
            #pragma unroll
            for (int d = 1; d < 16; d <<= 1) s += __shfl_xor(s, d);
            float rs = __frcp_rn(s);
            u16* pp = &Sb[rr * 232];
            #pragma unroll
            for (int c = 0; c < 14; c++)
                pp[l16 + c * 16] = f2bf(vals[c] * rs);
        }
    }
    __syncthreads();

    f32x4 oacc[2];
    {
        f32x4 z = {0.f, 0.f, 0.f, 0.f};
        oacc[0] = z; oacc[1] = z;
    }
    #pragma unroll
    for (int ks = 0; ks < 7; ks++) {
        bf16x8 pa = *(const bf16x8*)&Sb[(rg * 16 + m) * 232 + ks * 32 + quad * 8];
        __builtin_amdgcn_s_setprio(1);
        #pragma unroll
        for (int j = 0; j < 2; j++) {
            int nt = half * 2 + j;
            int ad = (nt * 16 + m) * 234 + ks * 32 + quad * 8;
            union { u32 u[4]; bf16x8 v; } vb;
            vb.u[0] = *(const u32*)&Kb[ad];
            vb.u[1] = *(const u32*)&Kb[ad + 2];
            vb.u[2] = *(const u32*)&Kb[ad + 4];
            vb.u[3] = *(const u32*)&Kb[ad + 6];
            oacc[j] = __builtin_amdgcn_mfma_f32_16x16x32_bf16(pa, vb.v, oacc[j], 0, 0, 0);
        }
        __builtin_amdgcn_s_setprio(0);
    }
    #pragma unroll
    for (int j = 0; j < 2; j++) {
        int nt = half * 2 + j;
        #pragma unroll
        for (int reg = 0; reg < 4; reg++) {
            int rr = rg * 16 + quad * 4 + reg;
            int tok = (ti + (rr >> 3)) * 32 + (tj + (rr & 7));
            ob[(size_t)(n * 1024 + tok) * 512 + h * 64 + nt * 16 + m] = f2bf(oacc[j][reg]);
        }
    }
}

extern "C" void kernel_launch(void* const* d_in, const int* in_sizes, int n_in,
                              void* d_out, int out_size, void* d_ws, size_t ws_size,
                              hipStream_t stream)
{
    const float *x = nullptr, *pos = nullptr, *cond = nullptr, *w_cond = nullptr,
                *w_qkv = nullptr, *scale = nullptr, *w_out = nullptr;
    for (int i = 0; i < n_in; i++) {
        switch (in_sizes[i]) {
            case 1048576: x      = (const float*)d_in[i]; break;  // 2*32*32*512
            case 2048:    pos    = (const float*)d_in[i]; break;  // 2*32*32*1
            case 1536:    cond   = (const float*)d_in[i]; break;  // 2*768
            case 393216:  w_cond = (const float*)d_in[i]; break;  // 512*768
            case 786432:  w_qkv  = (const float*)d_in[i]; break;  // 1536*512
            case 8:       scale  = (const float*)d_in[i]; break;  // 8
            case 262144:  w_out  = (const float*)d_in[i]; break;  // 512*512
            default: break;
        }
    }
    float* out = (float*)d_out;   // FLOAT32 output

    char* ws = (char*)d_ws;
    float* ns    = (float*)ws;                          // [2][512]
    u16*   wqkvb = (u16*)(ws + 12288);                  // [1536][512]  bf16
    u16*   woutb = (u16*)(ws + 12288 + 1572864);        // [512][512]   bf16
    u16*   xn    = (u16*)(ws + 12288 + 2097152);        // [2048][512]  bf16
    u16*   qp    = (u16*)(ws + 12288 + 4194304);        // [2][8][1024][64] bf16
    u16*   kp    = (u16*)(ws + 12288 + 6291456);        // same
    u16*   vp    = (u16*)(ws + 12288 + 8388608);        // same
    u16*   ob    = (u16*)(ws + 12288 + 10485760);       // [2048][512]  bf16

    void* args[] = {
        (void*)&cond, (void*)&w_cond, (void*)&w_qkv, (void*)&w_out,
        (void*)&x, (void*)&pos, (void*)&scale,
        (void*)&ns, (void*)&wqkvb, (void*)&woutb, (void*)&xn,
        (void*)&qp, (void*)&kp, (void*)&vp, (void*)&ob, (void*)&out
    };
    hipError_t e = hipLaunchCooperativeKernel((const void*)fused_all,
                                              dim3(256), dim3(512),
                                              args, 0, stream);
    if (e != hipSuccess) {
        // Fallback: proven 5-kernel pipeline
        cond_prepw_kernel<<<1280, 256, 0, stream>>>(cond, w_cond, ns, w_qkv, w_out, wqkvb, woutb);
        rms_kernel<<<512, 256, 0, stream>>>(x, ns, xn);
        gemm_qkv<<<dim3(32, 24), 256, 0, stream>>>(xn, wqkvb, pos, scale, qp, kp, vp);
        attn_mfma<<<256, 512, 0, stream>>>(qp, kp, vp, ob);
        gemm_out<<<dim3(32, 8), 256, 0, stream>>>(ob, woutb, out, x, 512, 512);
    }
}

// Round 4
// 108.568 us; speedup vs baseline: 2.2486x; 2.2486x over previous
//
#include <hip/hip_runtime.h>

typedef unsigned short u16;
typedef unsigned int u32;
typedef __bf16 bf16x8 __attribute__((ext_vector_type(8)));
typedef float f32x4 __attribute__((ext_vector_type(4)));

__device__ __forceinline__ float bf2f(u16 v) {
    union { u32 u; float f; } c; c.u = ((u32)v) << 16; return c.f;
}
__device__ __forceinline__ u16 f2bf(float f) {
    union { float f; u32 u; } c; c.f = f;
    u32 u = c.u + 0x7fffu + ((c.u >> 16) & 1u);   // RNE
    return (u16)(u >> 16);
}

// ---------------- K1: fully independent prep work, one dispatch.
// blocks [0,192):   wqkv scale+convert: block = (n, rowchunk rc of 256, colpanel p16 of 32 cols).
//                   ns for the 32 cols is recomputed in-block (cheap dot), wqkvb2[n][o][c] = bf16(W[o,c]*ns[n,c]).
// blocks [192,448): w_out -> bf16
// blocks [448,960): rmsnorm WITHOUT cond scale: xn = bf16(x * rsqrt(mean x^2 + eps))
__global__ __launch_bounds__(256) void prep_kernel(
    const float* __restrict__ cond, const float* __restrict__ w_cond,
    const float* __restrict__ w_qkv, const float* __restrict__ w_out,
    const float* __restrict__ x,
    u16* __restrict__ wqkvb2, u16* __restrict__ woutb, u16* __restrict__ xn)
{
    int b = blockIdx.x;
    int t = threadIdx.x;
    if (b < 192) {
        __shared__ float ns_s[32];
        int n  = b / 96;
        int rc = (b / 16) % 6;          // row chunk: rows rc*256 .. +255
        int p16 = b & 15;               // col panel: cols p16*32 .. +31
        int c0 = p16 * 32;
        // ns for 32 cols: thread t -> col c_local = t>>3, partial g = t&7 over 96 elems
        int cl = t >> 3, g = t & 7;
        const float* cp = cond + n * 768 + g * 96;
        const float* wp = w_cond + (size_t)(c0 + cl) * 768 + g * 96;
        float s = 0.f;
        #pragma unroll
        for (int j = 0; j < 24; j++) {
            float4 a = *(const float4*)(cp + j * 4);
            float4 w4 = *(const float4*)(wp + j * 4);
            s += a.x * w4.x + a.y * w4.y + a.z * w4.z + a.w * w4.w;
        }
        s += __shfl_xor(s, 1); s += __shfl_xor(s, 2); s += __shfl_xor(s, 4);
        if (g == 0) ns_s[cl] = s + 1.f;
        __syncthreads();
        // scale 256 rows x 32 cols
        #pragma unroll
        for (int i = 0; i < 8; i++) {
            int task = i * 256 + t;
            int row = rc * 256 + (task >> 3);
            int cg = task & 7;
            const float* src = w_qkv + (size_t)row * 512 + c0 + cg * 4;
            float4 v = *(const float4*)src;
            float s0 = ns_s[cg * 4], s1 = ns_s[cg * 4 + 1],
                  s2 = ns_s[cg * 4 + 2], s3 = ns_s[cg * 4 + 3];
            ushort4 o;
            o.x = f2bf(v.x * s0); o.y = f2bf(v.y * s1);
            o.z = f2bf(v.z * s2); o.w = f2bf(v.w * s3);
            *(ushort4*)(wqkvb2 + (size_t)n * 786432 + (size_t)row * 512 + c0 + cg * 4) = o;
        }
    } else if (b < 448) {
        size_t i4 = (size_t)(b - 192) * 1024 + t * 4;
        float4 v = *(const float4*)(w_out + i4);
        ushort4 o; o.x = f2bf(v.x); o.y = f2bf(v.y); o.z = f2bf(v.z); o.w = f2bf(v.w);
        *(ushort4*)(woutb + i4) = o;
    } else {
        int w = t >> 6, lane = t & 63;
        int p = (b - 448) * 4 + w;   // 0..2047
        const float* xp = x + (size_t)p * 512;
        float4 v0 = *(const float4*)(xp + lane * 4);
        float4 v1 = *(const float4*)(xp + 256 + lane * 4);
        float ss = v0.x * v0.x + v0.y * v0.y + v0.z * v0.z + v0.w * v0.w
                 + v1.x * v1.x + v1.y * v1.y + v1.z * v1.z + v1.w * v1.w;
        #pragma unroll
        for (int d = 1; d < 64; d <<= 1) ss += __shfl_xor(ss, d);
        float inv = rsqrtf(ss * (1.f / 512.f) + 1e-6f);
        ushort4 o0, o1;
        o0.x = f2bf(v0.x * inv); o0.y = f2bf(v0.y * inv);
        o0.z = f2bf(v0.z * inv); o0.w = f2bf(v0.w * inv);
        o1.x = f2bf(v1.x * inv); o1.y = f2bf(v1.y * inv);
        o1.z = f2bf(v1.z * inv); o1.w = f2bf(v1.w * inv);
        *(ushort4*)(xn + (size_t)p * 512 + lane * 4) = o0;
        *(ushort4*)(xn + (size_t)p * 512 + 256 + lane * 4) = o1;
    }
}

// ---------------- K2: qkv GEMM, 64x64 tile, BK=128 quad-staged (16 MFMA / 16 ds_read_b128 per step),
// B plane selected by token batch (ns folded into weights). q/k head-norm + RoPE fused in epilogue.
__global__ __launch_bounds__(256) void gemm_qkv(
    const u16* __restrict__ A, const u16* __restrict__ B,
    const float* __restrict__ pos, const float* __restrict__ scale,
    u16* __restrict__ qp, u16* __restrict__ kp, u16* __restrict__ vp)
{
    __shared__ __align__(16) u16 As[4][64][40];
    __shared__ __align__(16) u16 Bs[4][64][40];
    int tid = threadIdx.x;
    int lane = tid & 63;
    int w = tid >> 6;
    int wm = w >> 1, wn = w & 1;
    int bm = blockIdx.x * 64, bn = blockIdx.y * 64;
    int qk = blockIdx.y >> 3, h = blockIdx.y & 7;
    int lrow = tid >> 2, lc8 = (tid & 3) * 8;

    f32x4 zero = {0.f, 0.f, 0.f, 0.f};
    f32x4 acc[2][2];
    acc[0][0] = zero; acc[0][1] = zero; acc[1][0] = zero; acc[1][1] = zero;

    const u16* Ap = A + (size_t)(bm + lrow) * 512 + lc8;
    const u16* Bp = B + (size_t)(blockIdx.x >> 4) * 786432 + (size_t)(bn + lrow) * 512 + lc8;
    int m = lane & 15, quad = lane >> 4, kq = quad * 8;

    for (int k0 = 0; k0 < 512; k0 += 128) {
        #pragma unroll
        for (int s = 0; s < 4; s++) {
            *(uint4*)&As[s][lrow][lc8] = *(const uint4*)(Ap + k0 + s * 32);
            *(uint4*)&Bs[s][lrow][lc8] = *(const uint4*)(Bp + k0 + s * 32);
        }
        __syncthreads();
        #pragma unroll
        for (int kk = 0; kk < 4; kk++) {
            bf16x8 a0 = *(const bf16x8*)&As[kk][wm * 32 + m][kq];
            bf16x8 a1 = *(const bf16x8*)&As[kk][wm * 32 + 16 + m][kq];
            bf16x8 b0 = *(const bf16x8*)&Bs[kk][wn * 32 + m][kq];
            bf16x8 b1 = *(const bf16x8*)&Bs[kk][wn * 32 + 16 + m][kq];
            acc[0][0] = __builtin_amdgcn_mfma_f32_16x16x32_bf16(a0, b0, acc[0][0], 0, 0, 0);
            acc[0][1] = __builtin_amdgcn_mfma_f32_16x16x32_bf16(a0, b1, acc[0][1], 0, 0, 0);
            acc[1][0] = __builtin_amdgcn_mfma_f32_16x16x32_bf16(a1, b0, acc[1][0], 0, 0, 0);
            acc[1][1] = __builtin_amdgcn_mfma_f32_16x16x32_bf16(a1, b1, acc[1][1], 0, 0, 0);
        }
        __syncthreads();
    }

    // ---- epilogue: head-norm (sum over 64 cols via cross-wave LDS) + RoPE for q/k
    float invn[2][4];
    if (qk < 2) {
        float* red = (float*)As;   // [64][2] partials, reuse LDS
        #pragma unroll
        for (int ri = 0; ri < 2; ri++)
        #pragma unroll
        for (int reg = 0; reg < 4; reg++) {
            float pa = acc[ri][0][reg] * acc[ri][0][reg]
                     + acc[ri][1][reg] * acc[ri][1][reg];
            #pragma unroll
            for (int d = 1; d < 16; d <<= 1) pa += __shfl_xor(pa, d);
            if (m == 0) red[(wm * 32 + ri * 16 + quad * 4 + reg) * 2 + wn] = pa;
        }
        __syncthreads();
        float sq = sqrtf(scale[h]);
        #pragma unroll
        for (int ri = 0; ri < 2; ri++)
        #pragma unroll
        for (int reg = 0; reg < 4; reg++) {
            int rl = wm * 32 + ri * 16 + quad * 4 + reg;
            invn[ri][reg] = sq * rsqrtf(red[rl * 2] + red[rl * 2 + 1] + 1e-6f);
        }
    }
    u16* plane = (qk == 0) ? qp : (qk == 1) ? kp : vp;
    // freqs[h][t] = pi * 10^((t*8+h)/128), t = m
    float fr = 3.14159265358979323846f * expf((float)(m * 8 + h) * (2.302585092994046f / 128.f));
    #pragma unroll
    for (int ri = 0; ri < 2; ri++)
    #pragma unroll
    for (int reg = 0; reg < 4; reg++) {
        int rl = wm * 32 + ri * 16 + quad * 4 + reg;
        int p = bm + rl;
        size_t basep = ((size_t)((p >> 10) * 8 + h) * 1024 + (p & 1023)) * 64;
        float v0 = acc[ri][0][reg], v1 = acc[ri][1][reg];
        if (qk < 2) {
            float ivn = invn[ri][reg];
            v0 *= ivn; v1 *= ivn;
            if (wn == 0) {   // dims 0..31: rotate (d, d+16)
                float th = pos[p] * fr;
                float cs = cosf(th), sn = sinf(th);
                float o0 = v0 * cs - v1 * sn;
                float o1 = v1 * cs + v0 * sn;
                v0 = o0; v1 = o1;
            }
        }
        plane[basep + wn * 32 + m]      = f2bf(v0);
        plane[basep + wn * 32 + 16 + m] = f2bf(v1);
    }
}

// ---------------- K4: MFMA GEMM (out proj), BK=128 quad-staged: C fp32 = A @ B^T + skip
__global__ __launch_bounds__(256) void gemm_out(
    const u16* __restrict__ A, const u16* __restrict__ B,
    float* __restrict__ C, const float* __restrict__ skip, int N, int K)
{
    __shared__ __align__(16) u16 As[4][64][40];
    __shared__ __align__(16) u16 Bs[4][64][40];
    int tid = threadIdx.x;
    int lane = tid & 63;
    int w = tid >> 6;
    int wm = w >> 1, wn = w & 1;
    int bm = blockIdx.x * 64, bn = blockIdx.y * 64;
    int lrow = tid >> 2, lc8 = (tid & 3) * 8;

    f32x4 zero = {0.f, 0.f, 0.f, 0.f};
    f32x4 acc[2][2];
    acc[0][0] = zero; acc[0][1] = zero; acc[1][0] = zero; acc[1][1] = zero;

    const u16* Ap = A + (size_t)(bm + lrow) * K + lc8;
    const u16* Bp = B + (size_t)(bn + lrow) * K + lc8;
    int r = lane & 15, kq = (lane >> 4) * 8;

    for (int k0 = 0; k0 < K; k0 += 128) {
        #pragma unroll
        for (int s = 0; s < 4; s++) {
            *(uint4*)&As[s][lrow][lc8] = *(const uint4*)(Ap + k0 + s * 32);
            *(uint4*)&Bs[s][lrow][lc8] = *(const uint4*)(Bp + k0 + s * 32);
        }
        __syncthreads();
        #pragma unroll
        for (int kk = 0; kk < 4; kk++) {
            bf16x8 a0 = *(const bf16x8*)&As[kk][wm * 32 + r][kq];
            bf16x8 a1 = *(const bf16x8*)&As[kk][wm * 32 + 16 + r][kq];
            bf16x8 b0 = *(const bf16x8*)&Bs[kk][wn * 32 + r][kq];
            bf16x8 b1 = *(const bf16x8*)&Bs[kk][wn * 32 + 16 + r][kq];
            acc[0][0] = __builtin_amdgcn_mfma_f32_16x16x32_bf16(a0, b0, acc[0][0], 0, 0, 0);
            acc[0][1] = __builtin_amdgcn_mfma_f32_16x16x32_bf16(a0, b1, acc[0][1], 0, 0, 0);
            acc[1][0] = __builtin_amdgcn_mfma_f32_16x16x32_bf16(a1, b0, acc[1][0], 0, 0, 0);
            acc[1][1] = __builtin_amdgcn_mfma_f32_16x16x32_bf16(a1, b1, acc[1][1], 0, 0, 0);
        }
        __syncthreads();
    }

    #pragma unroll
    for (int ri = 0; ri < 2; ri++)
    #pragma unroll
    for (int ci = 0; ci < 2; ci++) {
        int col = bn + wn * 32 + ci * 16 + (lane & 15);
        int row0 = bm + wm * 32 + ri * 16 + (lane >> 4) * 4;
        #pragma unroll
        for (int reg = 0; reg < 4; reg++) {
            size_t idx = (size_t)(row0 + reg) * N + col;
            C[idx] = acc[ri][ci][reg] + skip[idx];
        }
    }
}

// ---------------- K3: MFMA neighborhood attention, 8 waves (512 thr) per block.
// One block per (n, h, 8x8 query tile). Union of neighborhoods = 14x14 = 196 keys.
__global__ __launch_bounds__(512) void attn_mfma(
    const u16* __restrict__ qp, const u16* __restrict__ kp, const u16* __restrict__ vp,
    u16* __restrict__ ob)
{
    __shared__ __align__(16) u16 Kb[208 * 72];   // K:[nb][64] stride 72; reused as Vt:[64][224] stride 234
    __shared__ __align__(16) u16 Sb[64 * 232];   // S fp16 then P bf16, row stride 232

    int tid = threadIdx.x, lane = tid & 63, w = tid >> 6;   // w 0..7
    int bx = blockIdx.x;
    int n = bx >> 7, h = (bx >> 4) & 7, t = bx & 15;
    int ti = (t >> 2) * 8, tj = (t & 3) * 8;
    int r0 = min(max(ti - 3, 0), 18), c0 = min(max(tj - 3, 0), 18);
    const u16* qpl = qp + ((size_t)(n * 8 + h) << 16);
    const u16* kpl = kp + ((size_t)(n * 8 + h) << 16);
    const u16* vpl = vp + ((size_t)(n * 8 + h) << 16);

    for (int g = tid; g < 1568; g += 512) {
        int nb = g >> 3, k8 = (g & 7) << 3;
        int ar = nb / 14, ac = nb - ar * 14;
        *(uint4*)&Kb[nb * 72 + k8] =
            *(const uint4*)&kpl[(size_t)((r0 + ar) * 32 + c0 + ac) * 64 + k8];
    }
    __syncthreads();

    int m = lane & 15, quad = lane >> 4;
    int rg = w & 3, half = w >> 2;
    {
        int r = rg * 16 + m;
        int tok = (ti + (r >> 3)) * 32 + (tj + (r & 7));
        bf16x8 qf0 = *(const bf16x8*)&qpl[(size_t)tok * 64 + quad * 8];
        bf16x8 qf1 = *(const bf16x8*)&qpl[(size_t)tok * 64 + 32 + quad * 8];
        _Float16* sp = (_Float16*)Sb;
        int ntb = half * 7;
        int ntn = 7 - half;          // half 0: nt 0..6, half 1: nt 7..12
        for (int i = 0; i < ntn; i++) {
            int nt = ntb + i;
            f32x4 acc = {0.f, 0.f, 0.f, 0.f};
            bf16x8 b0 = *(const bf16x8*)&Kb[(nt * 16 + m) * 72 + quad * 8];
            bf16x8 b1 = *(const bf16x8*)&Kb[(nt * 16 + m) * 72 + 32 + quad * 8];
            __builtin_amdgcn_s_setprio(1);
            acc = __builtin_amdgcn_mfma_f32_16x16x32_bf16(qf0, b0, acc, 0, 0, 0);
            acc = __builtin_amdgcn_mfma_f32_16x16x32_bf16(qf1, b1, acc, 0, 0, 0);
            __builtin_amdgcn_s_setprio(0);
            #pragma unroll
            for (int reg = 0; reg < 4; reg++)
                sp[(rg * 16 + quad * 4 + reg) * 232 + nt * 16 + m] = (_Float16)acc[reg];
        }
    }
    __syncthreads();

    // V -> transposed LDS (Vt[d][nb], stride 234), overwrite Kb
    for (int g = tid; g < 1568; g += 512) {
        int nb = g >> 3, k8 = (g & 7) << 3;
        int ar = nb / 14, ac = nb - ar * 14;
        uint4 v4 = *(const uint4*)&vpl[(size_t)((r0 + ar) * 32 + c0 + ac) * 64 + k8];
        u32 uu[4] = {v4.x, v4.y, v4.z, v4.w};
        #pragma unroll
        for (int e = 0; e < 4; e++) {
            Kb[(k8 + 2 * e) * 234 + nb]     = (u16)(uu[e] & 0xffff);
            Kb[(k8 + 2 * e + 1) * 234 + nb] = (u16)(uu[e] >> 16);
        }
    }
    for (int g = tid; g < 1792; g += 512) {
        int d = g / 28, nb = 196 + (g - d * 28);
        Kb[d * 234 + nb] = 0;
    }

    // softmax: each wave owns rows w*8 .. w*8+7
    {
        int l16 = lane & 15, g4 = lane >> 4;
        #pragma unroll
        for (int it = 0; it < 2; it++) {
            int rr = w * 8 + it * 4 + g4;
            int i2 = ti + (rr >> 3), j2 = tj + (rr & 7);
            int alo = min(max(i2 - 3, 0), 25) - r0;
            int blo = min(max(j2 - 3, 0), 25) - c0;
            const _Float16* sp = (const _Float16*)&Sb[rr * 232];
            float vals[14];
            float mx = -1e30f;
            #pragma unroll
            for (int c = 0; c < 14; c++) {
                int col = l16 + c * 16;
                float v = -1e30f;
                if (col < 196) {
                    int ar = col / 14, ac = col - ar * 14;
                    if (ar >= alo && ar < alo + 7 && ac >= blo && ac < blo + 7)
                        v = (float)sp[col];
                }
                vals[c] = v; mx = fmaxf(mx, v);
            }
            #pragma unroll
            for (int d = 1; d < 16; d <<= 1) mx = fmaxf(mx, __shfl_xor(mx, d));
            float s = 0.f;
            #pragma unroll
            for (int c = 0; c < 14; c++) {
                float e = exp2f((vals[c] - mx) * 1.44269504f);
                vals[c] = e; s += e;
            }
            #pragma unroll
            for (int d = 1; d < 16; d <<= 1) s += __shfl_xor(s, d);
            float rs = __frcp_rn(s);
            u16* pp = &Sb[rr * 232];
            #pragma unroll
            for (int c = 0; c < 14; c++)
                pp[l16 + c * 16] = f2bf(vals[c] * rs);
        }
    }
    __syncthreads();

    // PV: wave (rg, half): rows rg*16..+15, dims (half*2+j)*16..+15 for j=0,1
    f32x4 oacc[2];
    {
        f32x4 z = {0.f, 0.f, 0.f, 0.f};
        oacc[0] = z; oacc[1] = z;
    }
    #pragma unroll
    for (int ks = 0; ks < 7; ks++) {
        bf16x8 pa = *(const bf16x8*)&Sb[(rg * 16 + m) * 232 + ks * 32 + quad * 8];
        __builtin_amdgcn_s_setprio(1);
        #pragma unroll
        for (int j = 0; j < 2; j++) {
            int nt = half * 2 + j;
            int ad = (nt * 16 + m) * 234 + ks * 32 + quad * 8;
            union { u32 u[4]; bf16x8 v; } vb;
            vb.u[0] = *(const u32*)&Kb[ad];
            vb.u[1] = *(const u32*)&Kb[ad + 2];
            vb.u[2] = *(const u32*)&Kb[ad + 4];
            vb.u[3] = *(const u32*)&Kb[ad + 6];
            oacc[j] = __builtin_amdgcn_mfma_f32_16x16x32_bf16(pa, vb.v, oacc[j], 0, 0, 0);
        }
        __builtin_amdgcn_s_setprio(0);
    }
    #pragma unroll
    for (int j = 0; j < 2; j++) {
        int nt = half * 2 + j;
        #pragma unroll
        for (int reg = 0; reg < 4; reg++) {
            int rr = rg * 16 + quad * 4 + reg;
            int tok = (ti + (rr >> 3)) * 32 + (tj + (rr & 7));
            ob[(size_t)(n * 1024 + tok) * 512 + h * 64 + nt * 16 + m] = f2bf(oacc[j][reg]);
        }
    }
}

extern "C" void kernel_launch(void* const* d_in, const int* in_sizes, int n_in,
                              void* d_out, int out_size, void* d_ws, size_t ws_size,
                              hipStream_t stream)
{
    // Match inputs by unique element count (robust to ordering).
    const float *x = nullptr, *pos = nullptr, *cond = nullptr, *w_cond = nullptr,
                *w_qkv = nullptr, *scale = nullptr, *w_out = nullptr;
    for (int i = 0; i < n_in; i++) {
        switch (in_sizes[i]) {
            case 1048576: x      = (const float*)d_in[i]; break;  // 2*32*32*512
            case 2048:    pos    = (const float*)d_in[i]; break;  // 2*32*32*1
            case 1536:    cond   = (const float*)d_in[i]; break;  // 2*768
            case 393216:  w_cond = (const float*)d_in[i]; break;  // 512*768
            case 786432:  w_qkv  = (const float*)d_in[i]; break;  // 1536*512
            case 8:       scale  = (const float*)d_in[i]; break;  // 8
            case 262144:  w_out  = (const float*)d_in[i]; break;  // 512*512
            default: break;
        }
    }
    float* out = (float*)d_out;   // FLOAT32 output

    // ws: wqkvb2 3M | woutb .5M | xn 2M | qp/kp/vp 2M each | ob 2M
    char* ws = (char*)d_ws;
    u16* wqkvb2 = (u16*)ws;                        // [2][1536][512] bf16 (ns-folded)
    u16* woutb  = (u16*)(ws + 3145728);            // [512][512]   bf16
    u16* xn     = (u16*)(ws + 3670016);            // [2048][512]  bf16
    u16* qp     = (u16*)(ws + 5767168);            // [2][8][1024][64] bf16
    u16* kp     = (u16*)(ws + 7864320);            // same
    u16* vp     = (u16*)(ws + 9961472);            // same
    u16* ob     = (u16*)(ws + 12058624);           // [2048][512]  bf16

    prep_kernel<<<960, 256, 0, stream>>>(cond, w_cond, w_qkv, w_out, x, wqkvb2, woutb, xn);
    gemm_qkv<<<dim3(32, 24), 256, 0, stream>>>(xn, wqkvb2, pos, scale, qp, kp, vp);
    attn_mfma<<<256, 512, 0, stream>>>(qp, kp, vp, ob);
    gemm_out<<<dim3(32, 8), 256, 0, stream>>>(ob, woutb, out, x, 512, 512);
}

// Round 5
// 103.228 us; speedup vs baseline: 2.3650x; 1.0517x over previous
//
#include <hip/hip_runtime.h>

typedef unsigned short u16;
typedef unsigned int u32;
typedef __bf16 bf16x8 __attribute__((ext_vector_type(8)));
typedef float f32x4 __attribute__((ext_vector_type(4)));

__device__ __forceinline__ float bf2f(u16 v) {
    union { u32 u; float f; } c; c.u = ((u32)v) << 16; return c.f;
}
__device__ __forceinline__ u16 f2bf(float f) {
    union { float f; u32 u; } c; c.f = f;
    u32 u = c.u + 0x7fffu + ((c.u >> 16) & 1u);   // RNE
    return (u16)(u >> 16);
}

// async global->LDS, 16B per lane, dest = wave-uniform base + lane*16 (HW rule, m104)
#define GLDS16(gp, lp) __builtin_amdgcn_global_load_lds( \
    (const __attribute__((address_space(1))) void*)(gp), \
    (__attribute__((address_space(3))) void*)(lp), 16, 0, 0)

// ---------------- K1: blocks 0..255 cond_scale -> ns[2][512] | 256..1023 w_qkv->bf16 | 1024..1279 w_out->bf16
__global__ __launch_bounds__(256) void cond_prepw_kernel(
    const float* __restrict__ cond, const float* __restrict__ w_cond, float* __restrict__ ns,
    const float* __restrict__ w_qkv, const float* __restrict__ w_out,
    u16* __restrict__ wqkvb, u16* __restrict__ woutb)
{
    int b = blockIdx.x;
    if (b < 256) {
        int lane = threadIdx.x & 63;
        int wid = b * 4 + (threadIdx.x >> 6); // 0..1023
        int n = wid >> 9, c = wid & 511;
        const float* cp = cond + n * 768;
        const float* wp = w_cond + (size_t)c * 768;
        float s = 0.f;
        #pragma unroll
        for (int j = 0; j < 12; j++)
            s += cp[lane + j * 64] * wp[lane + j * 64];
        #pragma unroll
        for (int d = 1; d < 64; d <<= 1) s += __shfl_xor(s, d);
        if (lane == 0) ns[wid] = s + 1.f;
    } else {
        const float* src; u16* dst; size_t i4;
        if (b < 1024) { src = w_qkv; dst = wqkvb; i4 = (size_t)(b - 256)  * 1024 + threadIdx.x * 4; }
        else          { src = w_out; dst = woutb; i4 = (size_t)(b - 1024) * 1024 + threadIdx.x * 4; }
        float4 v = *(const float4*)(src + i4);
        ushort4 o; o.x = f2bf(v.x); o.y = f2bf(v.y); o.z = f2bf(v.z); o.w = f2bf(v.w);
        *(ushort4*)(dst + i4) = o;
    }
}

// ---------------- K2: rmsnorm (512 blocks, 4 token-rows each)
__global__ __launch_bounds__(256) void rms_kernel(
    const float* __restrict__ x, const float* __restrict__ ns, u16* __restrict__ xn)
{
    int b = blockIdx.x;
    int w = threadIdx.x >> 6, lane = threadIdx.x & 63;
    int p = b * 4 + w;   // 0..2047
    int n = p >> 10;
    const float* xp = x + (size_t)p * 512;
    const float* nsp = ns + n * 512;
    float4 v0 = *(const float4*)(xp + lane * 4);
    float4 v1 = *(const float4*)(xp + 256 + lane * 4);
    float ss = v0.x * v0.x + v0.y * v0.y + v0.z * v0.z + v0.w * v0.w
             + v1.x * v1.x + v1.y * v1.y + v1.z * v1.z + v1.w * v1.w;
    #pragma unroll
    for (int d = 1; d < 64; d <<= 1) ss += __shfl_xor(ss, d);
    float inv = rsqrtf(ss * (1.f / 512.f) + 1e-6f);
    float4 n0 = *(const float4*)(nsp + lane * 4);
    float4 n1 = *(const float4*)(nsp + 256 + lane * 4);
    ushort4 o0, o1;
    o0.x = f2bf(v0.x * n0.x * inv); o0.y = f2bf(v0.y * n0.y * inv);
    o0.z = f2bf(v0.z * n0.z * inv); o0.w = f2bf(v0.w * n0.w * inv);
    o1.x = f2bf(v1.x * n1.x * inv); o1.y = f2bf(v1.y * n1.y * inv);
    o1.z = f2bf(v1.z * n1.z * inv); o1.w = f2bf(v1.w * n1.w * inv);
    *(ushort4*)(xn + (size_t)p * 512 + lane * 4) = o0;
    *(ushort4*)(xn + (size_t)p * 512 + 256 + lane * 4) = o1;
}

// ---------------- K3: qkv GEMM, 64x64 tile, BK=128, global_load_lds staging (linear LDS,
// both-sides XOR swizzle: LDS (row, chunk) holds global chunk (chunk ^ ((row>>1)&3)), 16B chunks).
// q/k head-norm + RoPE fused in epilogue. Writes head-major bf16 planes.
__global__ __launch_bounds__(256) void gemm_qkv(
    const u16* __restrict__ A, const u16* __restrict__ B,
    const float* __restrict__ pos, const float* __restrict__ scale,
    u16* __restrict__ qp, u16* __restrict__ kp, u16* __restrict__ vp)
{
    __shared__ __align__(16) u16 As[4][64][32];
    __shared__ __align__(16) u16 Bs[4][64][32];
    int tid = threadIdx.x;
    int lane = tid & 63;
    int w = tid >> 6;
    int wm = w >> 1, wn = w & 1;
    int bm = blockIdx.x * 64, bn = blockIdx.y * 64;
    int qk = blockIdx.y >> 3, h = blockIdx.y & 7;

    // staging map: dest row r = w*16 + (lane>>2), dest chunk c = lane&3; source chunk = c ^ ((r>>1)&3)
    int r_st = w * 16 + (lane >> 2);
    int c_sw = (lane & 3) ^ ((r_st >> 1) & 3);
    const u16* Ap = A + (size_t)(bm + r_st) * 512 + c_sw * 8;
    const u16* Bp = B + (size_t)(bn + r_st) * 512 + c_sw * 8;

    f32x4 zero = {0.f, 0.f, 0.f, 0.f};
    f32x4 acc[2][2];
    acc[0][0] = zero; acc[0][1] = zero; acc[1][0] = zero; acc[1][1] = zero;

    int m = lane & 15, quad = lane >> 4;
    int kqs = (quad ^ ((m >> 1) & 3)) * 8;   // swizzled read chunk (same for all 4 fragments)

    for (int k0 = 0; k0 < 512; k0 += 128) {
        #pragma unroll
        for (int s = 0; s < 4; s++) {
            GLDS16(Ap + k0 + s * 32, (u16*)As + s * 2048 + w * 512);
            GLDS16(Bp + k0 + s * 32, (u16*)Bs + s * 2048 + w * 512);
        }
        __syncthreads();
        #pragma unroll
        for (int kk = 0; kk < 4; kk++) {
            bf16x8 a0 = *(const bf16x8*)&As[kk][wm * 32 + m][kqs];
            bf16x8 a1 = *(const bf16x8*)&As[kk][wm * 32 + 16 + m][kqs];
            bf16x8 b0 = *(const bf16x8*)&Bs[kk][wn * 32 + m][kqs];
            bf16x8 b1 = *(const bf16x8*)&Bs[kk][wn * 32 + 16 + m][kqs];
            acc[0][0] = __builtin_amdgcn_mfma_f32_16x16x32_bf16(a0, b0, acc[0][0], 0, 0, 0);
            acc[0][1] = __builtin_amdgcn_mfma_f32_16x16x32_bf16(a0, b1, acc[0][1], 0, 0, 0);
            acc[1][0] = __builtin_amdgcn_mfma_f32_16x16x32_bf16(a1, b0, acc[1][0], 0, 0, 0);
            acc[1][1] = __builtin_amdgcn_mfma_f32_16x16x32_bf16(a1, b1, acc[1][1], 0, 0, 0);
        }
        __syncthreads();
    }

    // ---- epilogue: head-norm (sum over 64 cols via cross-wave LDS) + RoPE for q/k
    float invn[2][4];
    if (qk < 2) {
        float* red = (float*)As;   // [64][2] partials, reuse LDS
        #pragma unroll
        for (int ri = 0; ri < 2; ri++)
        #pragma unroll
        for (int reg = 0; reg < 4; reg++) {
            float pa = acc[ri][0][reg] * acc[ri][0][reg]
                     + acc[ri][1][reg] * acc[ri][1][reg];
            #pragma unroll
            for (int d = 1; d < 16; d <<= 1) pa += __shfl_xor(pa, d);
            if (m == 0) red[(wm * 32 + ri * 16 + quad * 4 + reg) * 2 + wn] = pa;
        }
        __syncthreads();
        float sq = sqrtf(scale[h]);
        #pragma unroll
        for (int ri = 0; ri < 2; ri++)
        #pragma unroll
        for (int reg = 0; reg < 4; reg++) {
            int rl = wm * 32 + ri * 16 + quad * 4 + reg;
            invn[ri][reg] = sq * rsqrtf(red[rl * 2] + red[rl * 2 + 1] + 1e-6f);
        }
    }
    u16* plane = (qk == 0) ? qp : (qk == 1) ? kp : vp;
    // freqs[h][t] = pi * 10^((t*8+h)/128), t = m
    float fr = 3.14159265358979323846f * expf((float)(m * 8 + h) * (2.302585092994046f / 128.f));
    #pragma unroll
    for (int ri = 0; ri < 2; ri++)
    #pragma unroll
    for (int reg = 0; reg < 4; reg++) {
        int rl = wm * 32 + ri * 16 + quad * 4 + reg;
        int p = bm + rl;
        size_t basep = ((size_t)((p >> 10) * 8 + h) * 1024 + (p & 1023)) * 64;
        float v0 = acc[ri][0][reg], v1 = acc[ri][1][reg];
        if (qk < 2) {
            float ivn = invn[ri][reg];
            v0 *= ivn; v1 *= ivn;
            if (wn == 0) {   // dims 0..31: rotate (d, d+16)
                float th = pos[p] * fr;
                float cs = cosf(th), sn = sinf(th);
                float o0 = v0 * cs - v1 * sn;
                float o1 = v1 * cs + v0 * sn;
                v0 = o0; v1 = o1;
            }
        }
        plane[basep + wn * 32 + m]      = f2bf(v0);
        plane[basep + wn * 32 + 16 + m] = f2bf(v1);
    }
}

// ---------------- K5: MFMA GEMM (out proj), BK=128, global_load_lds staging (same swizzle):
// C fp32 = A @ B^T + skip
__global__ __launch_bounds__(256) void gemm_out(
    const u16* __restrict__ A, const u16* __restrict__ B,
    float* __restrict__ C, const float* __restrict__ skip, int N, int K)
{
    __shared__ __align__(16) u16 As[4][64][32];
    __shared__ __align__(16) u16 Bs[4][64][32];
    int tid = threadIdx.x;
    int lane = tid & 63;
    int w = tid >> 6;
    int wm = w >> 1, wn = w & 1;
    int bm = blockIdx.x * 64, bn = blockIdx.y * 64;

    int r_st = w * 16 + (lane >> 2);
    int c_sw = (lane & 3) ^ ((r_st >> 1) & 3);
    const u16* Ap = A + (size_t)(bm + r_st) * K + c_sw * 8;
    const u16* Bp = B + (size_t)(bn + r_st) * K + c_sw * 8;

    f32x4 zero = {0.f, 0.f, 0.f, 0.f};
    f32x4 acc[2][2];
    acc[0][0] = zero; acc[0][1] = zero; acc[1][0] = zero; acc[1][1] = zero;

    int m = lane & 15, quad = lane >> 4;
    int kqs = (quad ^ ((m >> 1) & 3)) * 8;

    for (int k0 = 0; k0 < K; k0 += 128) {
        #pragma unroll
        for (int s = 0; s < 4; s++) {
            GLDS16(Ap + k0 + s * 32, (u16*)As + s * 2048 + w * 512);
            GLDS16(Bp + k0 + s * 32, (u16*)Bs + s * 2048 + w * 512);
        }
        __syncthreads();
        #pragma unroll
        for (int kk = 0; kk < 4; kk++) {
            bf16x8 a0 = *(const bf16x8*)&As[kk][wm * 32 + m][kqs];
            bf16x8 a1 = *(const bf16x8*)&As[kk][wm * 32 + 16 + m][kqs];
            bf16x8 b0 = *(const bf16x8*)&Bs[kk][wn * 32 + m][kqs];
            bf16x8 b1 = *(const bf16x8*)&Bs[kk][wn * 32 + 16 + m][kqs];
            acc[0][0] = __builtin_amdgcn_mfma_f32_16x16x32_bf16(a0, b0, acc[0][0], 0, 0, 0);
            acc[0][1] = __builtin_amdgcn_mfma_f32_16x16x32_bf16(a0, b1, acc[0][1], 0, 0, 0);
            acc[1][0] = __builtin_amdgcn_mfma_f32_16x16x32_bf16(a1, b0, acc[1][0], 0, 0, 0);
            acc[1][1] = __builtin_amdgcn_mfma_f32_16x16x32_bf16(a1, b1, acc[1][1], 0, 0, 0);
        }
        __syncthreads();
    }

    #pragma unroll
    for (int ri = 0; ri < 2; ri++)
    #pragma unroll
    for (int ci = 0; ci < 2; ci++) {
        int col = bn + wn * 32 + ci * 16 + m;
        int row0 = bm + wm * 32 + ri * 16 + quad * 4;
        #pragma unroll
        for (int reg = 0; reg < 4; reg++) {
            size_t idx = (size_t)(row0 + reg) * N + col;
            C[idx] = acc[ri][ci][reg] + skip[idx];
        }
    }
}

// ---------------- K4: MFMA neighborhood attention, 8 waves (512 thr) per block.  (R1-proven, unchanged)
__global__ __launch_bounds__(512) void attn_mfma(
    const u16* __restrict__ qp, const u16* __restrict__ kp, const u16* __restrict__ vp,
    u16* __restrict__ ob)
{
    __shared__ __align__(16) u16 Kb[208 * 72];   // K:[nb][64] stride 72; reused as Vt:[64][224] stride 234
    __shared__ __align__(16) u16 Sb[64 * 232];   // S fp16 then P bf16, row stride 232

    int tid = threadIdx.x, lane = tid & 63, w = tid >> 6;   // w 0..7
    int bx = blockIdx.x;
    int n = bx >> 7, h = (bx >> 4) & 7, t = bx & 15;
    int ti = (t >> 2) * 8, tj = (t & 3) * 8;
    int r0 = min(max(ti - 3, 0), 18), c0 = min(max(tj - 3, 0), 18);
    const u16* qpl = qp + ((size_t)(n * 8 + h) << 16);
    const u16* kpl = kp + ((size_t)(n * 8 + h) << 16);
    const u16* vpl = vp + ((size_t)(n * 8 + h) << 16);

    for (int g = tid; g < 1568; g += 512) {
        int nb = g >> 3, k8 = (g & 7) << 3;
        int ar = nb / 14, ac = nb - ar * 14;
        *(uint4*)&Kb[nb * 72 + k8] =
            *(const uint4*)&kpl[(size_t)((r0 + ar) * 32 + c0 + ac) * 64 + k8];
    }
    __syncthreads();

    int m = lane & 15, quad = lane >> 4;
    int rg = w & 3, half = w >> 2;
    {
        int r = rg * 16 + m;
        int tok = (ti + (r >> 3)) * 32 + (tj + (r & 7));
        bf16x8 qf0 = *(const bf16x8*)&qpl[(size_t)tok * 64 + quad * 8];
        bf16x8 qf1 = *(const bf16x8*)&qpl[(size_t)tok * 64 + 32 + quad * 8];
        _Float16* sp = (_Float16*)Sb;
        int ntb = half * 7;
        int ntn = 7 - half;          // half 0: nt 0..6, half 1: nt 7..12
        for (int i = 0; i < ntn; i++) {
            int nt = ntb + i;
            f32x4 acc = {0.f, 0.f, 0.f, 0.f};
            bf16x8 b0 = *(const bf16x8*)&Kb[(nt * 16 + m) * 72 + quad * 8];
            bf16x8 b1 = *(const bf16x8*)&Kb[(nt * 16 + m) * 72 + 32 + quad * 8];
            __builtin_amdgcn_s_setprio(1);
            acc = __builtin_amdgcn_mfma_f32_16x16x32_bf16(qf0, b0, acc, 0, 0, 0);
            acc = __builtin_amdgcn_mfma_f32_16x16x32_bf16(qf1, b1, acc, 0, 0, 0);
            __builtin_amdgcn_s_setprio(0);
            #pragma unroll
            for (int reg = 0; reg < 4; reg++)
                sp[(rg * 16 + quad * 4 + reg) * 232 + nt * 16 + m] = (_Float16)acc[reg];
        }
    }
    __syncthreads();

    // V -> transposed LDS (Vt[d][nb], stride 234), overwrite Kb
    for (int g = tid; g < 1568; g += 512) {
        int nb = g >> 3, k8 = (g & 7) << 3;
        int ar = nb / 14, ac = nb - ar * 14;
        uint4 v4 = *(const uint4*)&vpl[(size_t)((r0 + ar) * 32 + c0 + ac) * 64 + k8];
        u32 uu[4] = {v4.x, v4.y, v4.z, v4.w};
        #pragma unroll
        for (int e = 0; e < 4; e++) {
            Kb[(k8 + 2 * e) * 234 + nb]     = (u16)(uu[e] & 0xffff);
            Kb[(k8 + 2 * e + 1) * 234 + nb] = (u16)(uu[e] >> 16);
        }
    }
    for (int g = tid; g < 1792; g += 512) {
        int d = g / 28, nb = 196 + (g - d * 28);
        Kb[d * 234 + nb] = 0;
    }

    // softmax: each wave owns rows w*8 .. w*8+7
    {
        int l16 = lane & 15, g4 = lane >> 4;
        #pragma unroll
        for (int it = 0; it < 2; it++) {
            int rr = w * 8 + it * 4 + g4;
            int i2 = ti + (rr >> 3), j2 = tj + (rr & 7);
            int alo = min(max(i2 - 3, 0), 25) - r0;
            int blo = min(max(j2 - 3, 0), 25) - c0;
            const _Float16* sp = (const _Float16*)&Sb[rr * 232];
            float vals[14];
            float mx = -1e30f;
            #pragma unroll
            for (int c = 0; c < 14; c++) {
                int col = l16 + c * 16;
                float v = -1e30f;
                if (col < 196) {
                    int ar = col / 14, ac = col - ar * 14;
                    if (ar >= alo && ar < alo + 7 && ac >= blo && ac < blo + 7)
                        v = (float)sp[col];
                }
                vals[c] = v; mx = fmaxf(mx, v);
            }
            #pragma unroll
            for (int d = 1; d < 16; d <<= 1) mx = fmaxf(mx, __shfl_xor(mx, d));
            float s = 0.f;
            #pragma unroll
            for (int c = 0; c < 14; c++) {
                float e = exp2f((vals[c] - mx) * 1.44269504f);
                vals[c] = e; s += e;
            }
            #pragma unroll
            for (int d = 1; d < 16; d <<= 1) s += __shfl_xor(s, d);
            float rs = __frcp_rn(s);
            u16* pp = &Sb[rr * 232];
            #pragma unroll
            for (int c = 0; c < 14; c++)
                pp[l16 + c * 16] = f2bf(vals[c] * rs);
        }
    }
    __syncthreads();

    // PV: wave (rg, half): rows rg*16..+15, dims (half*2+j)*16..+15 for j=0,1
    f32x4 oacc[2];
    {
        f32x4 z = {0.f, 0.f, 0.f, 0.f};
        oacc[0] = z; oacc[1] = z;
    }
    #pragma unroll
    for (int ks = 0; ks < 7; ks++) {
        bf16x8 pa = *(const bf16x8*)&Sb[(rg * 16 + m) * 232 + ks * 32 + quad * 8];
        __builtin_amdgcn_s_setprio(1);
        #pragma unroll
        for (int j = 0; j < 2; j++) {
            int nt = half * 2 + j;
            int ad = (nt * 16 + m) * 234 + ks * 32 + quad * 8;
            union { u32 u[4]; bf16x8 v; } vb;
            vb.u[0] = *(const u32*)&Kb[ad];
            vb.u[1] = *(const u32*)&Kb[ad + 2];
            vb.u[2] = *(const u32*)&Kb[ad + 4];
            vb.u[3] = *(const u32*)&Kb[ad + 6];
            oacc[j] = __builtin_amdgcn_mfma_f32_16x16x32_bf16(pa, vb.v, oacc[j], 0, 0, 0);
        }
        __builtin_amdgcn_s_setprio(0);
    }
    #pragma unroll
    for (int j = 0; j < 2; j++) {
        int nt = half * 2 + j;
        #pragma unroll
        for (int reg = 0; reg < 4; reg++) {
            int rr = rg * 16 + quad * 4 + reg;
            int tok = (ti + (rr >> 3)) * 32 + (tj + (rr & 7));
            ob[(size_t)(n * 1024 + tok) * 512 + h * 64 + nt * 16 + m] = f2bf(oacc[j][reg]);
        }
    }
}

extern "C" void kernel_launch(void* const* d_in, const int* in_sizes, int n_in,
                              void* d_out, int out_size, void* d_ws, size_t ws_size,
                              hipStream_t stream)
{
    // Match inputs by unique element count (robust to ordering).
    const float *x = nullptr, *pos = nullptr, *cond = nullptr, *w_cond = nullptr,
                *w_qkv = nullptr, *scale = nullptr, *w_out = nullptr;
    for (int i = 0; i < n_in; i++) {
        switch (in_sizes[i]) {
            case 1048576: x      = (const float*)d_in[i]; break;  // 2*32*32*512
            case 2048:    pos    = (const float*)d_in[i]; break;  // 2*32*32*1
            case 1536:    cond   = (const float*)d_in[i]; break;  // 2*768
            case 393216:  w_cond = (const float*)d_in[i]; break;  // 512*768
            case 786432:  w_qkv  = (const float*)d_in[i]; break;  // 1536*512
            case 8:       scale  = (const float*)d_in[i]; break;  // 8
            case 262144:  w_out  = (const float*)d_in[i]; break;  // 512*512
            default: break;
        }
    }
    float* out = (float*)d_out;   // FLOAT32 output

    // ws: ns 4K | wqkvb 1.5M | woutb .5M | xn 2M | qp/kp/vp 2M each | ob 2M
    char* ws = (char*)d_ws;
    float* ns    = (float*)ws;                          // [2][512]
    u16*   wqkvb = (u16*)(ws + 12288);                  // [1536][512]  bf16
    u16*   woutb = (u16*)(ws + 12288 + 1572864);        // [512][512]   bf16
    u16*   xn    = (u16*)(ws + 12288 + 2097152);        // [2048][512]  bf16
    u16*   qp    = (u16*)(ws + 12288 + 4194304);        // [2][8][1024][64] bf16
    u16*   kp    = (u16*)(ws + 12288 + 6291456);        // same
    u16*   vp    = (u16*)(ws + 12288 + 8388608);        // same
    u16*   ob    = (u16*)(ws + 12288 + 10485760);       // [2048][512]  bf16

    cond_prepw_kernel<<<1280, 256, 0, stream>>>(cond, w_cond, ns, w_qkv, w_out, wqkvb, woutb);
    rms_kernel<<<512, 256, 0, stream>>>(x, ns, xn);
    gemm_qkv<<<dim3(32, 24), 256, 0, stream>>>(xn, wqkvb, pos, scale, qp, kp, vp);
    attn_mfma<<<256, 512, 0, stream>>>(qp, kp, vp, ob);
    gemm_out<<<dim3(32, 8), 256, 0, stream>>>(ob, woutb, out, x, 512, 512);
}